// Round 16
// baseline (524.280 us; speedup 1.0000x reference)
//
#include <hip/hip_runtime.h>
#include <hip/hip_cooperative_groups.h>
#include <hip/hip_bf16.h>

namespace cg = cooperative_groups;

// Problem constants
#define NN 50000      // nodes
#define NE 800000     // edges
#define FD 4          // features
#define TD 12         // timesteps
#define CD 32         // channels
#define HD 12         // horizon
#define FT 48         // FD*TD
#define NBANK 8       // chain banks per node
#define NVB (NN/16)   // 3125 virtual gather blocks

// Workspace layout (4-byte element offsets)
#define OFF_HEAD   0                    // int[NBANK*NN]   chain heads
#define OFF_PAY    400000               // int4[NE] (row, w_bits, next, 0)
#define OFF_DIS    3600000              // float[NN]
#define OFF_XS     3650000              // float[NN*FT]  xs = dis[i]*x[i,:]
#define OFF_CST    6050000              // float[512]
// cst block: Az[128] @0, cz[32] @128, Ah[128] @160, ch[32] @288, probs[12] @320

// Shared-memory block used by the gather+GRU phase (16224 B)
struct SMem {
    int2  smeta[16][64];
    float sy[16][FT];
    float hbuf[16][CD];
    float sAz[128], sAh[128], sCz[32], sCh[32], sP[TD];
    float sWout[CD * HD], sBout[HD];
};

// ---------------------------------------------------------------------------
// cst precompute (one 256-thread block's worth of work).
// (H0 stays zero in the reference => R-gate dead; only top 32 rows of Wl*
//  matter:  Az = Wz@Wlz[0:32,:],  cz = blz + bz@Wlz[0:32,:],  same for h.)
// ---------------------------------------------------------------------------
__device__ __forceinline__ void dev_cst(int tid,
        const float* __restrict__ Wz, const float* __restrict__ bz,
        const float* __restrict__ Wlz, const float* __restrict__ blz,
        const float* __restrict__ Wh, const float* __restrict__ bh,
        const float* __restrict__ Wlh, const float* __restrict__ blh,
        const float* __restrict__ attention, float* __restrict__ cst) {
    if (tid < 128) {
        int f = tid >> 5, c = tid & 31;
        float s = 0.f, s2 = 0.f;
        #pragma unroll
        for (int k = 0; k < 32; ++k) {
            s  += Wz[f*32 + k] * Wlz[k*32 + c];
            s2 += Wh[f*32 + k] * Wlh[k*32 + c];
        }
        cst[tid]       = s;   // Az
        cst[160 + tid] = s2;  // Ah
    } else if (tid < 160) {
        int c = tid - 128;
        float s = blz[c], s2 = blh[c];
        #pragma unroll
        for (int k = 0; k < 32; ++k) {
            s  += bz[k] * Wlz[k*32 + c];
            s2 += bh[k] * Wlh[k*32 + c];
        }
        cst[128 + c] = s;   // cz
        cst[288 + c] = s2;  // ch
    } else if (tid == 160) {
        float m = -1e30f;
        for (int t = 0; t < TD; ++t) m = fmaxf(m, attention[t]);
        float e[TD], s = 0.f;
        #pragma unroll
        for (int t = 0; t < TD; ++t) { e[t] = __expf(attention[t] - m); s += e[t]; }
        float inv = 1.f / s;
        #pragma unroll
        for (int t = 0; t < TD; ++t) cst[320 + t] = e[t] * inv;
    }
}

// per-edge chain insert: 1 banked atomicExch + 1 coalesced 16B payload write
__device__ __forceinline__ void dev_build(int e, const int* __restrict__ ei,
                                          const float* __restrict__ w,
                                          int* __restrict__ head, int4* __restrict__ pay4) {
    int r = ei[e];
    int c = ei[NE + e];
    int old = atomicExch(&head[(e & (NBANK-1)) * NN + c], e);
    pay4[e] = make_int4(r, __float_as_int(w[e]), old, 0);
}

// weighted degree by chain walk (contention-free) -> dis -> xs scale.
// 16 lanes/node: lanes 0..7 walk one bank chain each, xor-reduce, broadcast.
__device__ __forceinline__ void dev_degdis_xs(int t, const int* __restrict__ head,
                                              const int4* __restrict__ pay4,
                                              const float* __restrict__ x,
                                              float* __restrict__ dis,
                                              float* __restrict__ xs) {
    int i = t >> 4;
    int g = t & 15;
    float s = 0.f;
    if (g < 8) {
        int e = head[g * NN + i];
        while (e >= 0) {
            int4 p = pay4[e];
            s += __int_as_float(p.y);
            e = p.z;
        }
    }
    s += __shfl_xor(s, 1, 8);
    s += __shfl_xor(s, 2, 8);
    s += __shfl_xor(s, 4, 8);
    float dsum = __shfl(s, 0, 16);       // lane 0 of the 16-lane window
    float di = rsqrtf(dsum + 1.0f);
    if (g == 0) dis[i] = di;
    const float3* x3 = (const float3*)x;
    float3 xv = x3[i * 16 + g];
    ((float3*)xs)[i * 16 + g] = make_float3(di * xv.x, di * xv.y, di * xv.z);
}

// load GRU constants into LDS (once per block)
__device__ __forceinline__ void dev_loadsm(int tid, SMem& sm, const float* __restrict__ cst,
                                           const float* __restrict__ Wout,
                                           const float* __restrict__ bout) {
    if (tid < 128) { sm.sAz[tid] = cst[tid]; sm.sAh[tid] = cst[160 + tid]; }
    if (tid < 32)  { sm.sCz[tid] = cst[128 + tid]; sm.sCh[tid] = cst[288 + tid]; }
    if (tid < TD)  { sm.sP[tid] = cst[320 + tid]; sm.sBout[tid] = bout[tid]; }
    for (int k = tid; k < CD * HD; k += 256) sm.sWout[k] = Wout[k];
}

// ---------------------------------------------------------------------------
// One virtual gather+GRU block (16 nodes). Identical to round-15's measured
// kernel body: chain stash -> shfl-scan -> compacted LDS list -> uniform
// unroll-8 gather over xs (all 16 lanes, float3 chunks) -> GRU -> out matvec.
// ---------------------------------------------------------------------------
__device__ __forceinline__ void dev_gather_vb(int vb, int tid, SMem& sm,
        const float* __restrict__ xs, const float* __restrict__ dis,
        const int* __restrict__ head, const int4* __restrict__ pay4,
        float* __restrict__ out) {
    int lane = tid & 63;
    int g  = tid & 15;
    int ln = tid >> 4;
    int i  = vb * 16 + ln;

    const float3* xs3 = (const float3*)xs;
    float d = dis[i];
    float3 a = xs3[i * 16 + g];
    float ax = a.x, ay = a.y, az = a.z;

    int e = (g < 8) ? head[g * NN + i] : -1;
    (void)lane;

    while (true) {
        int r0=0,r1=0,r2=0,r3=0,r4=0,r5=0,r6=0,r7=0;
        float n0=0,n1=0,n2=0,n3=0,n4=0,n5=0,n6=0,n7=0;
        int cnt = 0;
        #define STEP(RK,NK) if (e >= 0) { int4 p = pay4[e]; RK = p.x; \
            NK = __int_as_float(p.y); e = p.z; ++cnt; }
        STEP(r0,n0) STEP(r1,n1) STEP(r2,n2) STEP(r3,n3)
        STEP(r4,n4) STEP(r5,n5) STEP(r6,n6) STEP(r7,n7)
        #undef STEP

        int incl = cnt;
        #pragma unroll
        for (int dd = 1; dd < 8; dd <<= 1) {
            int t2 = __shfl_up(incl, dd, 16);
            if (g >= dd) incl += t2;
        }
        int S = __shfl(incl, 7, 16);
        if (S == 0) break;
        int off = incl - cnt;

        if (cnt > 0) sm.smeta[ln][off + 0] = make_int2(r0, __float_as_int(n0));
        if (cnt > 1) sm.smeta[ln][off + 1] = make_int2(r1, __float_as_int(n1));
        if (cnt > 2) sm.smeta[ln][off + 2] = make_int2(r2, __float_as_int(n2));
        if (cnt > 3) sm.smeta[ln][off + 3] = make_int2(r3, __float_as_int(n3));
        if (cnt > 4) sm.smeta[ln][off + 4] = make_int2(r4, __float_as_int(n4));
        if (cnt > 5) sm.smeta[ln][off + 5] = make_int2(r5, __float_as_int(n5));
        if (cnt > 6) sm.smeta[ln][off + 6] = make_int2(r6, __float_as_int(n6));
        if (cnt > 7) sm.smeta[ln][off + 7] = make_int2(r7, __float_as_int(n7));
        __builtin_amdgcn_wave_barrier();

        #pragma unroll 8
        for (int k = 0; k < S; ++k) {
            int2 m = sm.smeta[ln][k];
            float nv = __int_as_float(m.y);
            float3 v = xs3[m.x * 16 + g];
            ax += nv * v.x; ay += nv * v.y; az += nv * v.z;
        }
    }

    sm.sy[ln][g*3 + 0] = d * ax;
    sm.sy[ln][g*3 + 1] = d * ay;
    sm.sy[ln][g*3 + 2] = d * az;
    __syncthreads();

    // GRU, 2 channels per lane
    {
        int c0 = g, c1 = g + 16;
        float az00 = sm.sAz[c0], az01 = sm.sAz[32+c0], az02 = sm.sAz[64+c0], az03 = sm.sAz[96+c0];
        float az10 = sm.sAz[c1], az11 = sm.sAz[32+c1], az12 = sm.sAz[64+c1], az13 = sm.sAz[96+c1];
        float ah00 = sm.sAh[c0], ah01 = sm.sAh[32+c0], ah02 = sm.sAh[64+c0], ah03 = sm.sAh[96+c0];
        float ah10 = sm.sAh[c1], ah11 = sm.sAh[32+c1], ah12 = sm.sAh[64+c1], ah13 = sm.sAh[96+c1];
        float cz0 = sm.sCz[c0], cz1 = sm.sCz[c1], ch0 = sm.sCh[c0], ch1 = sm.sCh[c1];

        float hacc0 = 0.f, hacc1 = 0.f;
        #pragma unroll
        for (int t = 0; t < TD; ++t) {
            float y0 = sm.sy[ln][0*TD + t];
            float y1 = sm.sy[ln][1*TD + t];
            float y2 = sm.sy[ln][2*TD + t];
            float y3 = sm.sy[ln][3*TD + t];
            float z0 = cz0 + y0*az00 + y1*az01 + y2*az02 + y3*az03;
            float z1 = cz1 + y0*az10 + y1*az11 + y2*az12 + y3*az13;
            float h0 = ch0 + y0*ah00 + y1*ah01 + y2*ah02 + y3*ah03;
            float h1 = ch1 + y0*ah10 + y1*ah11 + y2*ah12 + y3*ah13;
            float Z0 = 1.f / (1.f + __expf(-z0));
            float Z1 = 1.f / (1.f + __expf(-z1));
            float e0 = __expf(2.f * h0);
            float e1 = __expf(2.f * h1);
            float H0v = (e0 - 1.f) / (e0 + 1.f);
            float H1v = (e1 - 1.f) / (e1 + 1.f);
            float p = sm.sP[t];
            hacc0 += p * (1.f - Z0) * H0v;
            hacc1 += p * (1.f - Z1) * H1v;
        }
        sm.hbuf[ln][c0] = fmaxf(hacc0, 0.f);
        sm.hbuf[ln][c1] = fmaxf(hacc1, 0.f);
    }
    __syncthreads();

    if (tid < 16 * HD) {
        int lnode = tid / HD, hor = tid - lnode * HD;
        int gn = vb * 16 + lnode;
        float s = sm.sBout[hor];
        #pragma unroll
        for (int k = 0; k < CD; ++k) s += sm.hbuf[lnode][k] * sm.sWout[k * HD + hor];
        out[gn * HD + hor] = s;
    }
    __syncthreads();   // protect sy/smeta/hbuf before next virtual block
}

// ---------------------------------------------------------------------------
// Cooperative mega-kernel: all phases, grid.sync between.
// ---------------------------------------------------------------------------
__global__ __launch_bounds__(256) void fused_all(
        const float* __restrict__ x, const int* __restrict__ ei,
        const float* __restrict__ ew,
        const float* __restrict__ Wz, const float* __restrict__ bz,
        const float* __restrict__ Wlz, const float* __restrict__ blz,
        const float* __restrict__ Wh, const float* __restrict__ bh,
        const float* __restrict__ Wlh, const float* __restrict__ blh,
        const float* __restrict__ attn,
        const float* __restrict__ Wout, const float* __restrict__ bout,
        int* __restrict__ head, int4* __restrict__ pay4,
        float* __restrict__ dis, float* __restrict__ xs,
        float* __restrict__ cst, float* __restrict__ out) {
    cg::grid_group grid = cg::this_grid();
    __shared__ SMem sm;
    int tid   = threadIdx.x;
    int gsize = gridDim.x * 256;
    int gtid  = blockIdx.x * 256 + tid;

    // P0: head = -1 ; block 0 computes cst
    for (int j = gtid; j < NBANK * NN; j += gsize) head[j] = -1;
    if (blockIdx.x == 0) dev_cst(tid, Wz, bz, Wlz, blz, Wh, bh, Wlh, blh, attn, cst);
    __threadfence();
    grid.sync();

    // P1: build chains
    for (int e = gtid; e < NE; e += gsize) dev_build(e, ei, ew, head, pay4);
    __threadfence();
    grid.sync();

    // P2: degree walk -> dis -> xs
    for (int t = gtid; t < NN * 16; t += gsize) dev_degdis_xs(t, head, pay4, x, dis, xs);
    __threadfence();
    grid.sync();

    // P3: gather + GRU + output over virtual blocks
    dev_loadsm(tid, sm, cst, Wout, bout);
    __syncthreads();
    for (int vb = blockIdx.x; vb < NVB; vb += gridDim.x)
        dev_gather_vb(vb, tid, sm, xs, dis, head, pay4, out);
}

// ---------------------------------------------------------------------------
// Fallback path: round-15's proven 4-launch pipeline (identical bodies).
// ---------------------------------------------------------------------------
__global__ void build_pre_kernel(const int* __restrict__ ei, const float* __restrict__ w,
                                 int* __restrict__ head, int4* __restrict__ pay4,
                                 const float* __restrict__ Wz, const float* __restrict__ bz,
                                 const float* __restrict__ Wlz, const float* __restrict__ blz,
                                 const float* __restrict__ Wh, const float* __restrict__ bh,
                                 const float* __restrict__ Wlh, const float* __restrict__ blh,
                                 const float* __restrict__ attention,
                                 float* __restrict__ cst) {
    int tid = threadIdx.x;
    if (blockIdx.x < (NE / 256)) {
        dev_build(blockIdx.x * 256 + tid, ei, w, head, pay4);
        return;
    }
    dev_cst(tid, Wz, bz, Wlz, blz, Wh, bh, Wlh, blh, attention, cst);
}

__global__ void degdis_xs_kernel(const int* __restrict__ head, const int4* __restrict__ pay4,
                                 const float* __restrict__ x, float* __restrict__ dis,
                                 float* __restrict__ xs) {
    dev_degdis_xs(blockIdx.x * blockDim.x + threadIdx.x, head, pay4, x, dis, xs);
}

__global__ __launch_bounds__(256) void gather_gru_kernel(
        const float* __restrict__ xs, const float* __restrict__ dis,
        const int* __restrict__ head, const int4* __restrict__ pay4,
        const float* __restrict__ cst, const float* __restrict__ Wout,
        const float* __restrict__ bout, float* __restrict__ out) {
    __shared__ SMem sm;
    int tid = threadIdx.x;
    dev_loadsm(tid, sm, cst, Wout, bout);
    __syncthreads();
    dev_gather_vb(blockIdx.x, tid, sm, xs, dis, head, pay4, out);
}

extern "C" void kernel_launch(void* const* d_in, const int* in_sizes, int n_in,
                              void* d_out, int out_size, void* d_ws, size_t ws_size,
                              hipStream_t stream) {
    const float* x      = (const float*)d_in[0];
    const int*   ei     = (const int*)d_in[1];    // int32, layout [rows..., cols...]
    const float* ew     = (const float*)d_in[2];
    const float* attn   = (const float*)d_in[3];
    const float* Wz     = (const float*)d_in[4];
    const float* bz     = (const float*)d_in[5];
    const float* Wlz    = (const float*)d_in[6];
    const float* blz    = (const float*)d_in[7];
    // d_in[8..11] = Wr, br, Wlr, blr — dead (H0 == 0 forever)
    const float* Wh     = (const float*)d_in[12];
    const float* bh     = (const float*)d_in[13];
    const float* Wlh    = (const float*)d_in[14];
    const float* blh    = (const float*)d_in[15];
    const float* Wout   = (const float*)d_in[16];
    const float* bout   = (const float*)d_in[17];
    float* out = (float*)d_out;

    float* ws   = (float*)d_ws;
    int*   head = (int*)(ws + OFF_HEAD);
    int4*  pay4 = (int4*)(ws + OFF_PAY);
    float* dis  = ws + OFF_DIS;
    float* xs   = ws + OFF_XS;
    float* cst  = ws + OFF_CST;

    bool coop_ok = false;
    int maxB = 0;
    if (hipOccupancyMaxActiveBlocksPerMultiprocessor(&maxB, fused_all, 256, 0) == hipSuccess
        && maxB > 0) {
        int grid = maxB * 256;              // 256 CUs on MI355X
        if (grid > 2048) grid = 2048;
        void* args[] = { (void*)&x, (void*)&ei, (void*)&ew,
                         (void*)&Wz, (void*)&bz, (void*)&Wlz, (void*)&blz,
                         (void*)&Wh, (void*)&bh, (void*)&Wlh, (void*)&blh,
                         (void*)&attn, (void*)&Wout, (void*)&bout,
                         (void*)&head, (void*)&pay4, (void*)&dis, (void*)&xs,
                         (void*)&cst, (void*)&out };
        hipError_t err = hipLaunchCooperativeKernel(fused_all, dim3(grid), dim3(256),
                                                    args, 0, stream);
        if (err == hipSuccess) coop_ok = true;
        else (void)hipGetLastError();       // clear sticky error, take fallback
    }

    if (!coop_ok) {
        hipMemsetAsync(head, 0xFF, NBANK * NN * sizeof(int), stream);   // head = -1
        build_pre_kernel<<<NE / 256 + 1, 256, 0, stream>>>(ei, ew, head, pay4,
                                                           Wz, bz, Wlz, blz,
                                                           Wh, bh, Wlh, blh, attn, cst);
        degdis_xs_kernel<<<NN * 16 / 256, 256, 0, stream>>>(head, pay4, x, dis, xs);
        gather_gru_kernel<<<NVB, 256, 0, stream>>>(xs, dis, head, pay4, cst,
                                                   Wout, bout, out);
    }
}